// Round 6
// baseline (241.873 us; speedup 1.0000x reference)
//
#include <hip/hip_runtime.h>

// Problem constants (frozen by the reference)
#define NN 16
#define CC 64
#define HH 128
#define WW 128

#define LDS_STRIDE 72      // bf16 elems per wp row (144 B; dword stride 36)
#define PANEL_DW   4752    // dwords per panel (19008 B)
#define ROW_BYTES  19008   // 132*72*2 bytes per xT row
#define ROW_CHUNKS 1188    // 16B chunks per xT row
#define T3B_STRIDE 132     // bf16 elems per t3b row (264 B)

typedef __attribute__((ext_vector_type(8))) short short8;   // bf16x8 (4 VGPRs)
typedef __attribute__((ext_vector_type(4))) float floatx4;  // MFMA C/D

__device__ __forceinline__ short f2bf(float f) {
    union { float f; unsigned u; } v; v.f = f;
    unsigned r = v.u + 0x7fffu + ((v.u >> 16) & 1u);
    return (short)(r >> 16);
}
__device__ __forceinline__ unsigned pack2bf(float lo, float hi) {
    union { float f; unsigned u; } a, b; a.f = lo; b.f = hi;
    unsigned ra = a.u + 0x7fffu + ((a.u >> 16) & 1u);
    unsigned rb = b.u + 0x7fffu + ((b.u >> 16) & 1u);
    return (ra >> 16) | (rb & 0xffff0000u);
}
__device__ __forceinline__ float bf2f(unsigned short u) {
    union { unsigned u; float f; } v; v.u = ((unsigned)u) << 16;
    return v.f;
}
// Async global->LDS DMA, 16 B/lane. LDS dest = wave-uniform base + lane*16
// (HW adds the lane offset); global src is per-lane. Drained by vmcnt.
__device__ __forceinline__ void gload_lds16(const void* g, void* l) {
    __builtin_amdgcn_global_load_lds(
        (const __attribute__((address_space(1))) void*)g,
        (__attribute__((address_space(3))) void*)l, 16, 0, 0);
}

// ---------------------------------------------------------------------------
// Kernel 0: pack w3 (co, ci, 1, 5) fp32 directly into MFMA A-fragment order:
// Apk[mh][ks][m][lane(64)][8 bf16], lane=(g*16+lm), so a wave's per-ks A-load
// is ONE coalesced 1KB global_load_dwordx4. Also zeroes the 256 B zero-page
// (d_ws re-poisoned before every launch, so rewrite every call).
// ---------------------------------------------------------------------------
__global__ __launch_bounds__(256) void prep_w(const float* __restrict__ w3,
                                              short* __restrict__ Apk,
                                              float* __restrict__ zp) {
    int idx = blockIdx.x * 256 + threadIdx.x;
    if (idx < CC * 320) {
        int co = idx / 320;
        int kk = idx % 320;
        int mh = co >> 5, m = (co >> 4) & 1, lm = co & 15;
        int ks = kk >> 5, g = (kk >> 3) & 3, e = kk & 7;
        int tap = kk >> 6, ci = kk & 63;
        Apk[((((mh * 10 + ks) * 2 + m) * 64) + (g * 16 + lm)) * 8 + e] =
            f2bf(w3[(co * CC + ci) * 5 + tap]);
    }
    if (blockIdx.x == 0 && threadIdx.x < 64) zp[threadIdx.x] = 0.f;
}

// ---------------------------------------------------------------------------
// Kernel 1: standalone transpose (unchanged, near-roofline ~106 MB).
// One block per (n, h-pair). Coalesced gather + in-lane pack + transposed
// LDS panel write, then linear coalesced dump to xT rows of 19008 B.
// ---------------------------------------------------------------------------
__global__ __launch_bounds__(256, 4) void transp(const float* __restrict__ x,
                                                 short* __restrict__ xT) {
    __shared__ __align__(16) char smem[2 * ROW_BYTES];   // 38016 B
    unsigned* xsW = (unsigned*)smem;   // dword view

    const int bid = blockIdx.x;
    const int rp  = ((bid & 7) << 7) | (bid >> 3);   // XCD-contiguous row pair
    const int n   = rp >> 6;
    const int h   = (rp & 63) * 2;                   // rows h, h+1
    const int tid = threadIdx.x;
    const int lane = tid & 63;
    const int W    = tid >> 6;

    {
        const int ri = lane >> 5;        // row within pair
        const int wq = lane & 31;        // w-quad
        unsigned* panel = xsW + ri * PANEL_DW;
        #pragma unroll
        for (int i = 0; i < 8; ++i) {
            const int cp = W * 8 + i;    // channel pair cp: ch 2cp, 2cp+1
            const float* b0 = x + (((size_t)(n * CC + 2 * cp)) * HH + h) * WW;
            float4 av = *(const float4*)(b0 + lane * 4);            // ch 2cp
            float4 bv = *(const float4*)(b0 + HH * WW + lane * 4);  // ch 2cp+1
            #pragma unroll
            for (int k = 0; k < 4; ++k) {
                int wp = wq * 4 + 2 + k;
                panel[wp * 36 + cp] = pack2bf(av[k], bv[k]);
            }
        }
        // zero pad rows wp in {0,1,130,131} of both panels
        {
            int pi  = tid >> 7;          // panel
            int idx = tid & 127;
            int wpi = idx >> 5;
            int wpz = (wpi < 2) ? wpi : 128 + wpi;
            xsW[pi * PANEL_DW + wpz * 36 + (idx & 31)] = 0u;
        }
    }
    __syncthreads();

    // linear dump: panel pi -> xT row (n, h+pi), coalesced 16B
    const size_t rowb = (size_t)(n * HH + h) * ROW_BYTES;
    #pragma unroll
    for (int pi = 0; pi < 2; ++pi) {
        short8* dst = (short8*)((char*)xT + rowb + (size_t)pi * ROW_BYTES);
        const short8* src = (const short8*)(smem + pi * ROW_BYTES);
        #pragma unroll
        for (int i = 0; i < 5; ++i) {
            int c = tid + 256 * i;
            if (c < ROW_CHUNKS) dst[c] = src[c];
        }
    }
}

// ---------------------------------------------------------------------------
// Kernel 2: fused GEMM + combine. One block per (n,h) row; 2048 blocks;
// LDS 19456 B, VGPR target <=64 -> 8 blocks/CU (2x every prior combine).
// Stage: xT row -> LDS via global_load_lds width=16 (no VGPR round trip).
// GEMM: 2x2 wave split, coalesced 1KB Apk A-loads, panel B from LDS.
// t3 handoff: through LDS t3b (aliases the dead panel) -- NO global t3
//   round-trip (saves 67 MB vs the split) and out is written exactly once.
// Combine: identical math to the verified standalone kernel; t3 read from
//   LDS instead of global.
// ---------------------------------------------------------------------------
__global__ __launch_bounds__(256, 8) void fused(const short* __restrict__ xT,
                                                const short* __restrict__ Apk,
                                                const float* __restrict__ x,
                                                const float* __restrict__ w7,
                                                const float* __restrict__ zp,
                                                float* __restrict__ out) {
    __shared__ __align__(16) char smem[19456];
    const short* panel = (const short*)smem;   // phases 1-2
    short*       t3b  = (short*)smem;          // phases 3-4 (aliases panel)

    const int bid = blockIdx.x;
    const int nh  = ((bid & 7) << 8) | (bid >> 3);   // XCD-contiguous h
    const int n   = nh >> 7;
    const int h   = nh & (HH - 1);
    const int tid = threadIdx.x;
    const int lane = tid & 63;
    const int W    = tid >> 6;

    // ---- stage row (19008 B) via async DMA; chunk-group = k2*4 + W ----
    {
        const char* grow = (const char*)xT + (size_t)(n * HH + h) * ROW_BYTES;
        #pragma unroll
        for (int k2 = 0; k2 < 5; ++k2) {
            int base = (k2 * 4 + W) * 1024;          // wave-uniform LDS byte base
            if (base < ROW_BYTES) {                  // skip all-garbage group 19
                int goff = base + lane * 16;         // per-lane global offset
                if (goff > ROW_BYTES - 16) goff = ROW_BYTES - 16;   // tail clamp
                gload_lds16(grow + goff, smem + base);
            }
        }
    }
    __syncthreads();   // drains vmcnt -> LDS panel valid

    // ---- GEMM: MFMA, 2x2 wave split ----
    const int lm = lane & 15;
    const int g  = lane >> 4;
    const int mh = W >> 1;           // co half: co-tiles {2mh, 2mh+1}
    const int wh = W & 1;            // w half:  j-tiles wh*4 .. wh*4+3

    floatx4 acc[2][4];
    #pragma unroll
    for (int m = 0; m < 2; ++m)
        #pragma unroll
        for (int j = 0; j < 4; ++j) acc[m][j] = (floatx4){0.f, 0.f, 0.f, 0.f};

    for (int ks = 0; ks < 10; ++ks) {
        const int kbase = ks * 32 + g * 8;
        const int tap   = kbase >> 6;
        const int cib   = kbase & 63;

        const short* ab = Apk + (((mh * 10 + ks) * 2) * 64 + lane) * 8;
        short8 a0 = *(const short8*)ab;                 // m=0, coalesced 1KB
        short8 a1 = *(const short8*)(ab + 64 * 8);      // m=1, coalesced 1KB
        #pragma unroll
        for (int j = 0; j < 4; ++j) {
            int wp = (wh * 4 + j) * 16 + lm + tap;
            short8 b = *(const short8*)&panel[wp * LDS_STRIDE + cib];
            acc[0][j] = __builtin_amdgcn_mfma_f32_16x16x32_bf16(a0, b, acc[0][j], 0, 0, 0);
            acc[1][j] = __builtin_amdgcn_mfma_f32_16x16x32_bf16(a1, b, acc[1][j], 0, 0, 0);
        }
    }
    __syncthreads();   // all waves done READING panel; t3b may now alias it

    // ---- epilogue: acc -> t3b (bf16) in LDS ----
    #pragma unroll
    for (int m = 0; m < 2; ++m)
        #pragma unroll
        for (int j = 0; j < 4; ++j)
            #pragma unroll
            for (int r = 0; r < 4; ++r) {
                int co = (mh * 2 + m) * 16 + g * 4 + r;
                int w  = (wh * 4 + j) * 16 + lm;
                t3b[co * T3B_STRIDE + w] = f2bf(acc[m][j][r]);
            }

    // ---- combine setup (global window pointers) ----
    const int w0  = (tid & 31) * 4;
    const int chi = tid >> 5;           // c = it*8 + chi
    const bool isw = (w0 == 0);
    const int src  = lane | 31;         // shfl source for roll-wrap values

    const float* p[9];
    int s[9];
    const float* xb0 = x + (((size_t)(n * CC + chi)) * HH) * WW;
    #pragma unroll
    for (int r = 0; r < 3; ++r) {
        int hh = h + r - 1;
        bool hok = (unsigned)hh < HH;
        #pragma unroll
        for (int q = 0; q < 3; ++q) {
            int cb = w0 - 4 + q * 4;
            bool ok = hok && (unsigned)cb < WW;
            p[r * 3 + q] = ok ? (xb0 + (size_t)hh * WW + cb) : zp;
            s[r * 3 + q] = ok ? (8 * HH * WW) : 0;
        }
    }
    const float* wcp = w7 + chi * 9;
    int t3o = chi * T3B_STRIDE + w0;
    float* outp = out + ((((size_t)(n * CC + chi)) * HH + h) * WW) + w0;

    __syncthreads();   // t3b fully written

    // ---- combine: 8 iterations x 8 channels ----
    #pragma unroll
    for (int it = 0; it < 8; ++it) {
        float4 cur[9];
        #pragma unroll
        for (int t = 0; t < 9; ++t) { cur[t] = *(const float4*)p[t]; p[t] += s[t]; }
        float wc[9];
        #pragma unroll
        for (int t = 0; t < 9; ++t) wc[t] = wcp[t];
        ushort4 tv = *(const ushort4*)&t3b[t3o];

        // window view: win[r][q*4+k] = col w0-4+q*4+k of row h+r-1
        float win[3][12];
        #pragma unroll
        for (int r = 0; r < 3; ++r) {
            #pragma unroll
            for (int q = 0; q < 3; ++q) {
                float4 v = cur[r * 3 + q];
                win[r][q * 4 + 0] = v.x; win[r][q * 4 + 1] = v.y;
                win[r][q * 4 + 2] = v.z; win[r][q * 4 + 3] = v.w;
            }
        }
        // wrap values (w==0 roll): cols 125,127 live in lane (lane|31)'s q=1 quad
        float wrap0[3], wrap1[3];
        #pragma unroll
        for (int r = 0; r < 3; ++r) {
            wrap0[r] = __shfl(win[r][5], src);
            wrap1[r] = __shfl(win[r][7], src);
        }

        float t3v[4] = {bf2f(tv.x), bf2f(tv.y), bf2f(tv.z), bf2f(tv.w)};

        float res[4];
        #pragma unroll
        for (int e = 0; e < 4; ++e) {
            float a = 0.f;
            #pragma unroll
            for (int j = 0; j < 3; ++j) {
                #pragma unroll
                for (int i = 0; i < 3; ++i) {
                    float lhs = win[1][e + 2 * i + 2];        // col w+2(i-1)
                    float rhs = win[i][e + 2 * j + 1];        // col w+2j-3
                    if (e == 0)
                        rhs = isw ? ((j == 0) ? wrap0[i]
                                   : (j == 1) ? wrap1[i] : 0.f)
                                  : rhs;
                    a = fmaf(wc[j * 3 + i], fmaxf(lhs, rhs), a);
                }
            }
            res[e] = a;
        }
        float4 o;
        o.x = res[0] * t3v[0]; o.y = res[1] * t3v[1];
        o.z = res[2] * t3v[2]; o.w = res[3] * t3v[3];
        *(float4*)outp = o;

        // advance per-iteration state (8 channels per iteration step)
        wcp  += 8 * 9;
        t3o  += 8 * T3B_STRIDE;
        outp += (size_t)8 * HH * WW;
    }
}

extern "C" void kernel_launch(void* const* d_in, const int* in_sizes, int n_in,
                              void* d_out, int out_size, void* d_ws, size_t ws_size,
                              hipStream_t stream) {
    const float* x  = (const float*)d_in[0];
    const float* w3 = (const float*)d_in[1];
    const float* w7 = (const float*)d_in[2];
    float* out = (float*)d_out;

    short* Apk = (short*)d_ws;                       // 40960 B packed A
    float* zp  = (float*)((char*)d_ws + 40960);      // 256 B zero page
    short* xT  = (short*)((char*)d_ws + 65536);      // 38,928,384 B transposed x

    prep_w<<<(CC * 320 + 255) / 256, 256, 0, stream>>>(w3, Apk, zp);
    transp<<<NN * HH / 2, 256, 0, stream>>>(x, xT);
    fused<<<NN * HH, 256, 0, stream>>>(xT, Apk, x, w7, zp, out);
}

// Round 8
// 148.111 us; speedup vs baseline: 1.6330x; 1.6330x over previous
//
#include <hip/hip_runtime.h>

// Problem constants (frozen by the reference)
#define NN 16
#define CC 64
#define HH 128
#define WW 128

#define LDS_STRIDE 72      // bf16 elems per wp row (144 B; dword stride 36)
#define PANEL_DW   4752    // dwords per panel (19008 B)
#define ROW_BYTES  19008   // 132*72*2 bytes per xT row
#define ROW_CHUNKS 1188    // 16B chunks per xT row
#define T3B_STRIDE 132     // bf16 elems per t3b row (264 B)

typedef __attribute__((ext_vector_type(8))) short short8;   // bf16x8 (4 VGPRs)
typedef __attribute__((ext_vector_type(4))) float floatx4;  // MFMA C/D

__device__ __forceinline__ short f2bf(float f) {
    union { float f; unsigned u; } v; v.f = f;
    unsigned r = v.u + 0x7fffu + ((v.u >> 16) & 1u);
    return (short)(r >> 16);
}
__device__ __forceinline__ unsigned pack2bf(float lo, float hi) {
    union { float f; unsigned u; } a, b; a.f = lo; b.f = hi;
    unsigned ra = a.u + 0x7fffu + ((a.u >> 16) & 1u);
    unsigned rb = b.u + 0x7fffu + ((b.u >> 16) & 1u);
    return (ra >> 16) | (rb & 0xffff0000u);
}
__device__ __forceinline__ float bf2f(unsigned short u) {
    union { unsigned u; float f; } v; v.u = ((unsigned)u) << 16;
    return v.f;
}
// Async global->LDS DMA, 16 B/lane. LDS dest = wave-uniform base + lane*16
// (HW adds the lane offset); global src is per-lane. Drained by vmcnt.
__device__ __forceinline__ void gload_lds16(const void* g, void* l) {
    __builtin_amdgcn_global_load_lds(
        (const __attribute__((address_space(1))) void*)g,
        (__attribute__((address_space(3))) void*)l, 16, 0, 0);
}

// ---------------------------------------------------------------------------
// Kernel 0: pack w3 (co, ci, 1, 5) fp32 directly into MFMA A-fragment order:
// Apk[mh][ks][m][lane(64)][8 bf16], lane=(g*16+lm), so a wave's per-ks A-load
// is ONE coalesced 1KB global_load_dwordx4. Also zeroes the 256 B zero-page
// (d_ws re-poisoned before every launch, so rewrite every call).
// ---------------------------------------------------------------------------
__global__ __launch_bounds__(256) void prep_w(const float* __restrict__ w3,
                                              short* __restrict__ Apk,
                                              float* __restrict__ zp) {
    int idx = blockIdx.x * 256 + threadIdx.x;
    if (idx < CC * 320) {
        int co = idx / 320;
        int kk = idx % 320;
        int mh = co >> 5, m = (co >> 4) & 1, lm = co & 15;
        int ks = kk >> 5, g = (kk >> 3) & 3, e = kk & 7;
        int tap = kk >> 6, ci = kk & 63;
        Apk[((((mh * 10 + ks) * 2 + m) * 64) + (g * 16 + lm)) * 8 + e] =
            f2bf(w3[(co * CC + ci) * 5 + tap]);
    }
    if (blockIdx.x == 0 && threadIdx.x < 64) zp[threadIdx.x] = 0.f;
}

// ---------------------------------------------------------------------------
// Kernel 1: standalone transpose (unchanged, near-roofline ~106 MB).
// One block per (n, h-pair). Coalesced gather + in-lane pack + transposed
// LDS panel write, then linear coalesced dump to xT rows of 19008 B.
// ---------------------------------------------------------------------------
__global__ __launch_bounds__(256, 4) void transp(const float* __restrict__ x,
                                                 short* __restrict__ xT) {
    __shared__ __align__(16) char smem[2 * ROW_BYTES];   // 38016 B
    unsigned* xsW = (unsigned*)smem;   // dword view

    const int bid = blockIdx.x;
    const int rp  = ((bid & 7) << 7) | (bid >> 3);   // XCD-contiguous row pair
    const int n   = rp >> 6;
    const int h   = (rp & 63) * 2;                   // rows h, h+1
    const int tid = threadIdx.x;
    const int lane = tid & 63;
    const int W    = tid >> 6;

    {
        const int ri = lane >> 5;        // row within pair
        const int wq = lane & 31;        // w-quad
        unsigned* panel = xsW + ri * PANEL_DW;
        #pragma unroll
        for (int i = 0; i < 8; ++i) {
            const int cp = W * 8 + i;    // channel pair cp: ch 2cp, 2cp+1
            const float* b0 = x + (((size_t)(n * CC + 2 * cp)) * HH + h) * WW;
            float4 av = *(const float4*)(b0 + lane * 4);            // ch 2cp
            float4 bv = *(const float4*)(b0 + HH * WW + lane * 4);  // ch 2cp+1
            #pragma unroll
            for (int k = 0; k < 4; ++k) {
                int wp = wq * 4 + 2 + k;
                panel[wp * 36 + cp] = pack2bf(av[k], bv[k]);
            }
        }
        // zero pad rows wp in {0,1,130,131} of both panels
        {
            int pi  = tid >> 7;          // panel
            int idx = tid & 127;
            int wpi = idx >> 5;
            int wpz = (wpi < 2) ? wpi : 128 + wpi;
            xsW[pi * PANEL_DW + wpz * 36 + (idx & 31)] = 0u;
        }
    }
    __syncthreads();

    // linear dump: panel pi -> xT row (n, h+pi), coalesced 16B
    const size_t rowb = (size_t)(n * HH + h) * ROW_BYTES;
    #pragma unroll
    for (int pi = 0; pi < 2; ++pi) {
        short8* dst = (short8*)((char*)xT + rowb + (size_t)pi * ROW_BYTES);
        const short8* src = (const short8*)(smem + pi * ROW_BYTES);
        #pragma unroll
        for (int i = 0; i < 5; ++i) {
            int c = tid + 256 * i;
            if (c < ROW_CHUNKS) dst[c] = src[c];
        }
    }
}

// ---------------------------------------------------------------------------
// Kernel 2: fused GEMM + combine. One block per (n,h) row; 2048 blocks;
// LDS 19456 B; __launch_bounds__(256,6) (VGPR cap ~85; (256,8)'s cap of 64
// forced R6's 304 MB scratch spill).
// Combine uses the register-lean window scheme (3 loads/iter + neighbor
// shfls). R7 LESSON: every __shfl must be an UNCONDITIONAL top-level
// statement -- `cond ? 0 : __shfl(...)` puts the convergent ds_bpermute
// under divergent exec, and lanes whose SOURCE lane is masked off (lanes
// 1/33 reading 0/32, 30/62 reading 31/63) read undefined data (absmax
// 10.8 failure). Shfl first with full exec, select after.
// ---------------------------------------------------------------------------
__global__ __launch_bounds__(256, 6) void fused(const short* __restrict__ xT,
                                                const short* __restrict__ Apk,
                                                const float* __restrict__ x,
                                                const float* __restrict__ w7,
                                                const float* __restrict__ zp,
                                                float* __restrict__ out) {
    __shared__ __align__(16) char smem[19456];
    const short* panel = (const short*)smem;   // phases 1-2
    short*       t3b  = (short*)smem;          // phases 3-4 (aliases panel)

    const int bid = blockIdx.x;
    const int nh  = ((bid & 7) << 8) | (bid >> 3);   // XCD-contiguous h
    const int n   = nh >> 7;
    const int h   = nh & (HH - 1);
    const int tid = threadIdx.x;
    const int lane = tid & 63;
    const int W    = tid >> 6;

    // ---- stage row (19008 B) via async DMA; chunk-group = k2*4 + W ----
    {
        const char* grow = (const char*)xT + (size_t)(n * HH + h) * ROW_BYTES;
        #pragma unroll
        for (int k2 = 0; k2 < 5; ++k2) {
            int base = (k2 * 4 + W) * 1024;          // wave-uniform LDS byte base
            if (base < ROW_BYTES) {                  // skip all-garbage group 19
                int goff = base + lane * 16;         // per-lane global offset
                if (goff > ROW_BYTES - 16) goff = ROW_BYTES - 16;   // tail clamp
                gload_lds16(grow + goff, smem + base);
            }
        }
    }
    __syncthreads();   // drains vmcnt -> LDS panel valid

    // ---- GEMM: MFMA, 2x2 wave split ----
    const int lm = lane & 15;
    const int g  = lane >> 4;
    const int mh = W >> 1;           // co half: co-tiles {2mh, 2mh+1}
    const int wh = W & 1;            // w half:  j-tiles wh*4 .. wh*4+3

    floatx4 acc[2][4];
    #pragma unroll
    for (int m = 0; m < 2; ++m)
        #pragma unroll
        for (int j = 0; j < 4; ++j) acc[m][j] = (floatx4){0.f, 0.f, 0.f, 0.f};

    for (int ks = 0; ks < 10; ++ks) {
        const int kbase = ks * 32 + g * 8;
        const int tap   = kbase >> 6;
        const int cib   = kbase & 63;

        const short* ab = Apk + (((mh * 10 + ks) * 2) * 64 + lane) * 8;
        short8 a0 = *(const short8*)ab;                 // m=0, coalesced 1KB
        short8 a1 = *(const short8*)(ab + 64 * 8);      // m=1, coalesced 1KB
        #pragma unroll
        for (int j = 0; j < 4; ++j) {
            int wp = (wh * 4 + j) * 16 + lm + tap;
            short8 b = *(const short8*)&panel[wp * LDS_STRIDE + cib];
            acc[0][j] = __builtin_amdgcn_mfma_f32_16x16x32_bf16(a0, b, acc[0][j], 0, 0, 0);
            acc[1][j] = __builtin_amdgcn_mfma_f32_16x16x32_bf16(a1, b, acc[1][j], 0, 0, 0);
        }
    }
    __syncthreads();   // all waves done READING panel; t3b may now alias it

    // ---- epilogue: acc -> t3b (bf16) in LDS ----
    #pragma unroll
    for (int m = 0; m < 2; ++m)
        #pragma unroll
        for (int j = 0; j < 4; ++j)
            #pragma unroll
            for (int r = 0; r < 4; ++r) {
                int co = (mh * 2 + m) * 16 + g * 4 + r;
                int w  = (wh * 4 + j) * 16 + lm;
                t3b[co * T3B_STRIDE + w] = f2bf(acc[m][j][r]);
            }

    // ---- combine setup ----
    const int w0   = (tid & 31) * 4;
    const int chi  = tid >> 5;            // c = it*8 + chi
    const int lq31 = lane & 31;
    const bool isw = (lq31 == 0);         // w0 == 0
    const bool ise = (lq31 == 31);        // w0 == 124
    const int src31 = lane | 31;          // wrap source (owns cols 124..127)
    const int lsrc  = isw ? lane : lane - 1;
    const int rsrc  = ise ? lane : lane + 1;

    const float* pr[3]; int sr[3];
    const float* xb0 = x + (((size_t)(n * CC + chi)) * HH) * WW;
    #pragma unroll
    for (int r = 0; r < 3; ++r) {
        int hh = h + r - 1;
        bool hok = (unsigned)hh < HH;     // block-uniform per r
        pr[r] = hok ? (xb0 + (size_t)hh * WW + w0) : zp;
        sr[r] = hok ? (8 * HH * WW) : 0;
    }
    const float* wcp = w7 + chi * 9;
    int t3o = chi * T3B_STRIDE + w0;
    float* outp = out + ((((size_t)(n * CC + chi)) * HH + h) * WW) + w0;

    __syncthreads();   // t3b fully written

    // window-row builder: dst[t] = col w0-4+t of the row held in quad c.
    // ALL shfls unconditional (full exec), selects applied afterwards.
    #define BUILD_WIN(dst, c)                                              \
        {                                                                  \
            float l1_ = __shfl((c).y, lsrc);                               \
            float l2_ = __shfl((c).z, lsrc);                               \
            float l3_ = __shfl((c).w, lsrc);                               \
            float r8_ = __shfl((c).x, rsrc);                               \
            float r9_ = __shfl((c).y, rsrc);                               \
            dst[1] = isw ? 0.f : l1_;                                      \
            dst[2] = isw ? 0.f : l2_;                                      \
            dst[3] = isw ? 0.f : l3_;                                      \
            dst[4] = (c).x; dst[5] = (c).y; dst[6] = (c).z; dst[7] = (c).w;\
            dst[8] = ise ? 0.f : r8_;                                      \
            dst[9] = ise ? 0.f : r9_;                                      \
        }

    // ---- combine: 8 iterations x 8 channels ----
    #pragma unroll
    for (int it = 0; it < 8; ++it) {
        float4 cur[3];
        #pragma unroll
        for (int r = 0; r < 3; ++r) { cur[r] = *(const float4*)pr[r]; pr[r] += sr[r]; }
        float wc[9];
        #pragma unroll
        for (int t = 0; t < 9; ++t) wc[t] = wcp[t];
        ushort4 tv = *(const ushort4*)&t3b[t3o];

        // roll-wrap values (w==0): cols 125,127 = lane|31's own .y/.w
        float wrap0[3], wrap1[3];
        #pragma unroll
        for (int r = 0; r < 3; ++r) {
            wrap0[r] = __shfl(cur[r].y, src31);
            wrap1[r] = __shfl(cur[r].w, src31);
        }

        // win1 = row h window, cols w0-3..w0+5 (indices 1..9)
        float win1[12];
        BUILD_WIN(win1, cur[1]);

        float t3v[4] = {bf2f(tv.x), bf2f(tv.y), bf2f(tv.z), bf2f(tv.w)};

        float res[4] = {0.f, 0.f, 0.f, 0.f};
        #pragma unroll
        for (int i = 0; i < 3; ++i) {          // i = h-offset row (outer)
            float wini[12];
            if (i == 1) {
                #pragma unroll
                for (int t = 1; t < 10; ++t) wini[t] = win1[t];
            } else {
                BUILD_WIN(wini, cur[i]);
            }
            #pragma unroll
            for (int j = 0; j < 3; ++j) {
                #pragma unroll
                for (int e = 0; e < 4; ++e) {
                    float lhs = win1[e + 2 * i + 2];      // col w+2(i-1), row h
                    float rhs = wini[e + 2 * j + 1];      // col w+2j-3, row h+i-1
                    if (e == 0)
                        rhs = isw ? ((j == 0) ? wrap0[i]
                                   : (j == 1) ? wrap1[i] : 0.f)
                                  : rhs;
                    res[e] = fmaf(wc[j * 3 + i], fmaxf(lhs, rhs), res[e]);
                }
            }
        }
        float4 o;
        o.x = res[0] * t3v[0]; o.y = res[1] * t3v[1];
        o.z = res[2] * t3v[2]; o.w = res[3] * t3v[3];
        *(float4*)outp = o;

        // advance per-iteration state (8 channels per iteration step)
        wcp  += 8 * 9;
        t3o  += 8 * T3B_STRIDE;
        outp += (size_t)8 * HH * WW;
    }
    #undef BUILD_WIN
}

extern "C" void kernel_launch(void* const* d_in, const int* in_sizes, int n_in,
                              void* d_out, int out_size, void* d_ws, size_t ws_size,
                              hipStream_t stream) {
    const float* x  = (const float*)d_in[0];
    const float* w3 = (const float*)d_in[1];
    const float* w7 = (const float*)d_in[2];
    float* out = (float*)d_out;

    short* Apk = (short*)d_ws;                       // 40960 B packed A
    float* zp  = (float*)((char*)d_ws + 40960);      // 256 B zero page
    short* xT  = (short*)((char*)d_ws + 65536);      // 38,928,384 B transposed x

    prep_w<<<(CC * 320 + 255) / 256, 256, 0, stream>>>(w3, Apk, zp);
    transp<<<NN * HH / 2, 256, 0, stream>>>(x, xT);
    fused<<<NN * HH, 256, 0, stream>>>(xT, Apk, x, w7, zp, out);
}

// Round 9
// 140.307 us; speedup vs baseline: 1.7239x; 1.0556x over previous
//
#include <hip/hip_runtime.h>

// Problem constants (frozen by the reference)
#define NN 16
#define CC 64
#define HH 128
#define WW 128

#define LDS_STRIDE 72      // bf16 elems per wp row (144 B; dword stride 36)
#define T3B_STRIDE 132     // bf16 elems per t3b row (264 B)

typedef __attribute__((ext_vector_type(8))) short short8;   // bf16x8 (4 VGPRs)
typedef __attribute__((ext_vector_type(4))) float floatx4;  // MFMA C/D

__device__ __forceinline__ short f2bf(float f) {
    union { float f; unsigned u; } v; v.f = f;
    unsigned r = v.u + 0x7fffu + ((v.u >> 16) & 1u);
    return (short)(r >> 16);
}
__device__ __forceinline__ unsigned pack2bf(float lo, float hi) {
    union { float f; unsigned u; } a, b; a.f = lo; b.f = hi;
    unsigned ra = a.u + 0x7fffu + ((a.u >> 16) & 1u);
    unsigned rb = b.u + 0x7fffu + ((b.u >> 16) & 1u);
    return (ra >> 16) | (rb & 0xffff0000u);
}
__device__ __forceinline__ float bf2f(unsigned short u) {
    union { unsigned u; float f; } v; v.u = ((unsigned)u) << 16;
    return v.f;
}

// ---------------------------------------------------------------------------
// Kernel 0: pack w3 (co, ci, 1, 5) fp32 directly into MFMA A-fragment order:
// Apk[mh][ks][m][lane(64)][8 bf16], lane=(g*16+lm), so a wave's per-ks A-load
// is ONE coalesced 1KB global_load_dwordx4. Also zeroes the 256 B zero-page
// (d_ws re-poisoned before every launch, so rewrite every call).
// ---------------------------------------------------------------------------
__global__ __launch_bounds__(256) void prep_w(const float* __restrict__ w3,
                                              short* __restrict__ Apk,
                                              float* __restrict__ zp) {
    int idx = blockIdx.x * 256 + threadIdx.x;
    if (idx < CC * 320) {
        int co = idx / 320;
        int kk = idx % 320;
        int mh = co >> 5, m = (co >> 4) & 1, lm = co & 15;
        int ks = kk >> 5, g = (kk >> 3) & 3, e = kk & 7;
        int tap = kk >> 6, ci = kk & 63;
        Apk[((((mh * 10 + ks) * 2 + m) * 64) + (g * 16 + lm)) * 8 + e] =
            f2bf(w3[(co * CC + ci) * 5 + tap]);
    }
    if (blockIdx.x == 0 && threadIdx.x < 64) zp[threadIdx.x] = 0.f;
}

// ---------------------------------------------------------------------------
// Kernel 1: fully fused gather + GEMM + combine. One block per (n,h) row;
// 2048 blocks; LDS 19456 B; __launch_bounds__(256,6) (VGPR cap ~85 --
// (256,8)'s cap of 64 caused R6's 304 MB scratch spill).
//
// Phase 1 (in-kernel gather, replaces the transp kernel + 78 MB xT
//   round-trip): half-wave = 32 lanes read one channel's 512 B row
//   contiguously (R4-proven coalescing, single-row variant). Thread
//   (W, half=lane>>5, wq=lane&31), i=0..3: cp = W*8 + i*2 + half; loads
//   float4 of channels 2cp and 2cp+1 at w=wq*4, packs bf16 pairs in-lane,
//   writes panel dwords [wp*36+cp], wp=wq*4+2+k. 16-way LDS write
//   conflicts accepted (~N/2.8 cost on a 2-cy op; a few us total).
//   R4's slowness was its 1024-block grid == residency (no turnover),
//   not the gather: here the grid is 2048 and combine adds overlap work.
// Phase 2 GEMM: 2x2 wave split, coalesced 1KB Apk A-loads, panel B.
// Phase 3: acc -> t3b bf16 in LDS (aliases dead panel; no global t3).
// Phase 4 combine: register-lean window scheme (3 loads/iter + neighbor
//   shfls). All shfls UNCONDITIONAL (R7 lesson: shfl under divergent
//   exec reads masked-off source lanes -> garbage), selects after.
// ---------------------------------------------------------------------------
__global__ __launch_bounds__(256, 6) void fused(const short* __restrict__ Apk,
                                                const float* __restrict__ x,
                                                const float* __restrict__ w7,
                                                const float* __restrict__ zp,
                                                float* __restrict__ out) {
    __shared__ __align__(16) char smem[19456];
    unsigned*    xsW  = (unsigned*)smem;       // dword view, stride 36
    const short* panel = (const short*)smem;   // phases 1-2
    short*       t3b  = (short*)smem;          // phases 3-4 (aliases panel)

    const int bid = blockIdx.x;
    const int nh  = ((bid & 7) << 8) | (bid >> 3);   // XCD-contiguous h
    const int n   = nh >> 7;
    const int h   = nh & (HH - 1);
    const int tid = threadIdx.x;
    const int lane = tid & 63;
    const int W    = tid >> 6;

    // ---- Phase 1: coalesced single-row gather + in-lane pack ----
    {
        const int half = lane >> 5;      // channel-pair select within wave
        const int wq   = lane & 31;      // w-quad
        const float* rowbase = x + ((size_t)n * CC * HH + h) * WW;
        #pragma unroll
        for (int i = 0; i < 4; ++i) {
            const int cp = W * 8 + i * 2 + half;     // channel pair
            const float* b0 = rowbase + (size_t)(2 * cp) * (HH * WW);
            float4 av = *(const float4*)(b0 + wq * 4);            // ch 2cp
            float4 bv = *(const float4*)(b0 + HH * WW + wq * 4);  // ch 2cp+1
            #pragma unroll
            for (int k = 0; k < 4; ++k) {
                int wp = wq * 4 + 2 + k;
                xsW[wp * 36 + cp] = pack2bf(av[k], bv[k]);
            }
        }
        if (tid < 128) {    // zero pad rows wp in {0,1,130,131}
            int wpi = tid >> 5;
            int wpz = (wpi < 2) ? wpi : 128 + wpi;
            xsW[wpz * 36 + (tid & 31)] = 0u;
        }
    }
    __syncthreads();

    // ---- Phase 2: GEMM, MFMA 2x2 wave split ----
    const int lm = lane & 15;
    const int g  = lane >> 4;
    const int mh = W >> 1;           // co half: co-tiles {2mh, 2mh+1}
    const int wh = W & 1;            // w half:  j-tiles wh*4 .. wh*4+3

    floatx4 acc[2][4];
    #pragma unroll
    for (int m = 0; m < 2; ++m)
        #pragma unroll
        for (int j = 0; j < 4; ++j) acc[m][j] = (floatx4){0.f, 0.f, 0.f, 0.f};

    for (int ks = 0; ks < 10; ++ks) {
        const int kbase = ks * 32 + g * 8;
        const int tap   = kbase >> 6;
        const int cib   = kbase & 63;

        const short* ab = Apk + (((mh * 10 + ks) * 2) * 64 + lane) * 8;
        short8 a0 = *(const short8*)ab;                 // m=0, coalesced 1KB
        short8 a1 = *(const short8*)(ab + 64 * 8);      // m=1, coalesced 1KB
        #pragma unroll
        for (int j = 0; j < 4; ++j) {
            int wp = (wh * 4 + j) * 16 + lm + tap;
            short8 b = *(const short8*)&panel[wp * LDS_STRIDE + cib];
            acc[0][j] = __builtin_amdgcn_mfma_f32_16x16x32_bf16(a0, b, acc[0][j], 0, 0, 0);
            acc[1][j] = __builtin_amdgcn_mfma_f32_16x16x32_bf16(a1, b, acc[1][j], 0, 0, 0);
        }
    }
    __syncthreads();   // all waves done READING panel; t3b may now alias it

    // ---- Phase 3: epilogue: acc -> t3b (bf16) in LDS ----
    #pragma unroll
    for (int m = 0; m < 2; ++m)
        #pragma unroll
        for (int j = 0; j < 4; ++j)
            #pragma unroll
            for (int r = 0; r < 4; ++r) {
                int co = (mh * 2 + m) * 16 + g * 4 + r;
                int w  = (wh * 4 + j) * 16 + lm;
                t3b[co * T3B_STRIDE + w] = f2bf(acc[m][j][r]);
            }

    // ---- combine setup ----
    const int w0   = (tid & 31) * 4;
    const int chi  = tid >> 5;            // c = it*8 + chi
    const int lq31 = lane & 31;
    const bool isw = (lq31 == 0);         // w0 == 0
    const bool ise = (lq31 == 31);        // w0 == 124
    const int src31 = lane | 31;          // wrap source (owns cols 124..127)
    const int lsrc  = isw ? lane : lane - 1;
    const int rsrc  = ise ? lane : lane + 1;

    const float* pr[3]; int sr[3];
    const float* xb0 = x + (((size_t)(n * CC + chi)) * HH) * WW;
    #pragma unroll
    for (int r = 0; r < 3; ++r) {
        int hh = h + r - 1;
        bool hok = (unsigned)hh < HH;     // block-uniform per r
        pr[r] = hok ? (xb0 + (size_t)hh * WW + w0) : zp;
        sr[r] = hok ? (8 * HH * WW) : 0;
    }
    const float* wcp = w7 + chi * 9;
    int t3o = chi * T3B_STRIDE + w0;
    float* outp = out + ((((size_t)(n * CC + chi)) * HH + h) * WW) + w0;

    __syncthreads();   // t3b fully written

    // window-row builder: dst[t] = col w0-4+t of the row held in quad c.
    // ALL shfls unconditional (full exec), selects applied afterwards.
    #define BUILD_WIN(dst, c)                                              \
        {                                                                  \
            float l1_ = __shfl((c).y, lsrc);                               \
            float l2_ = __shfl((c).z, lsrc);                               \
            float l3_ = __shfl((c).w, lsrc);                               \
            float r8_ = __shfl((c).x, rsrc);                               \
            float r9_ = __shfl((c).y, rsrc);                               \
            dst[1] = isw ? 0.f : l1_;                                      \
            dst[2] = isw ? 0.f : l2_;                                      \
            dst[3] = isw ? 0.f : l3_;                                      \
            dst[4] = (c).x; dst[5] = (c).y; dst[6] = (c).z; dst[7] = (c).w;\
            dst[8] = ise ? 0.f : r8_;                                      \
            dst[9] = ise ? 0.f : r9_;                                      \
        }

    // ---- Phase 4: combine, 8 iterations x 8 channels ----
    #pragma unroll
    for (int it = 0; it < 8; ++it) {
        float4 cur[3];
        #pragma unroll
        for (int r = 0; r < 3; ++r) { cur[r] = *(const float4*)pr[r]; pr[r] += sr[r]; }
        float wc[9];
        #pragma unroll
        for (int t = 0; t < 9; ++t) wc[t] = wcp[t];
        ushort4 tv = *(const ushort4*)&t3b[t3o];

        // roll-wrap values (w==0): cols 125,127 = lane|31's own .y/.w
        float wrap0[3], wrap1[3];
        #pragma unroll
        for (int r = 0; r < 3; ++r) {
            wrap0[r] = __shfl(cur[r].y, src31);
            wrap1[r] = __shfl(cur[r].w, src31);
        }

        // win1 = row h window, cols w0-3..w0+5 (indices 1..9)
        float win1[12];
        BUILD_WIN(win1, cur[1]);

        float t3v[4] = {bf2f(tv.x), bf2f(tv.y), bf2f(tv.z), bf2f(tv.w)};

        float res[4] = {0.f, 0.f, 0.f, 0.f};
        #pragma unroll
        for (int i = 0; i < 3; ++i) {          // i = h-offset row (outer)
            float wini[12];
            if (i == 1) {
                #pragma unroll
                for (int t = 1; t < 10; ++t) wini[t] = win1[t];
            } else {
                BUILD_WIN(wini, cur[i]);
            }
            #pragma unroll
            for (int j = 0; j < 3; ++j) {
                #pragma unroll
                for (int e = 0; e < 4; ++e) {
                    float lhs = win1[e + 2 * i + 2];      // col w+2(i-1), row h
                    float rhs = wini[e + 2 * j + 1];      // col w+2j-3, row h+i-1
                    if (e == 0)
                        rhs = isw ? ((j == 0) ? wrap0[i]
                                   : (j == 1) ? wrap1[i] : 0.f)
                                  : rhs;
                    res[e] = fmaf(wc[j * 3 + i], fmaxf(lhs, rhs), res[e]);
                }
            }
        }
        float4 o;
        o.x = res[0] * t3v[0]; o.y = res[1] * t3v[1];
        o.z = res[2] * t3v[2]; o.w = res[3] * t3v[3];
        *(float4*)outp = o;

        // advance per-iteration state (8 channels per iteration step)
        wcp  += 8 * 9;
        t3o  += 8 * T3B_STRIDE;
        outp += (size_t)8 * HH * WW;
    }
    #undef BUILD_WIN
}

extern "C" void kernel_launch(void* const* d_in, const int* in_sizes, int n_in,
                              void* d_out, int out_size, void* d_ws, size_t ws_size,
                              hipStream_t stream) {
    const float* x  = (const float*)d_in[0];
    const float* w3 = (const float*)d_in[1];
    const float* w7 = (const float*)d_in[2];
    float* out = (float*)d_out;

    short* Apk = (short*)d_ws;                       // 40960 B packed A
    float* zp  = (float*)((char*)d_ws + 40960);      // 256 B zero page

    prep_w<<<(CC * 320 + 255) / 256, 256, 0, stream>>>(w3, Apk, zp);
    fused<<<NN * HH, 256, 0, stream>>>(Apk, x, w7, zp, out);
}

// Round 11
// 138.497 us; speedup vs baseline: 1.7464x; 1.0131x over previous
//
#include <hip/hip_runtime.h>

// Problem constants (frozen by the reference)
#define NN 16
#define CC 64
#define HH 128
#define WW 128

#define LDS_STRIDE 72      // bf16 elems per wp row (144 B; dword stride 36)
#define T3B_STRIDE 132     // bf16 elems per t3b row (264 B)
#define WCS_OFF    16896   // byte offset of w7 stage (after t3b: 64*132*2)

typedef __attribute__((ext_vector_type(8))) short short8;   // bf16x8 (4 VGPRs)
typedef __attribute__((ext_vector_type(4))) float floatx4;  // MFMA C/D

__device__ __forceinline__ short f2bf(float f) {
    union { float f; unsigned u; } v; v.f = f;
    unsigned r = v.u + 0x7fffu + ((v.u >> 16) & 1u);
    return (short)(r >> 16);
}
__device__ __forceinline__ unsigned pack2bf(float lo, float hi) {
    union { float f; unsigned u; } a, b; a.f = lo; b.f = hi;
    unsigned ra = a.u + 0x7fffu + ((a.u >> 16) & 1u);
    unsigned rb = b.u + 0x7fffu + ((b.u >> 16) & 1u);
    return (ra >> 16) | (rb & 0xffff0000u);
}
__device__ __forceinline__ float bf2f(unsigned short u) {
    union { unsigned u; float f; } v; v.u = ((unsigned)u) << 16;
    return v.f;
}
// Prefetch load the compiler's waitcnt machinery does NOT track. The
// "memory" clobber is ESSENTIAL (R10 lesson): without it LLVM may hoist
// later tracked stores ABOVE these loads, breaking the manual vmcnt(N)
// accounting (vmcnt retires in ISSUE order). Caller owns the waitcnt.
__device__ __forceinline__ void gload4(float4& d, const float* p) {
    asm volatile("global_load_dwordx4 %0, %1, off"
                 : "=&v"(d) : "v"(p) : "memory");
}

// ---------------------------------------------------------------------------
// Kernel 0: pack w3 (co, ci, 1, 5) fp32 directly into MFMA A-fragment order:
// Apk[mh][ks][m][lane(64)][8 bf16], lane=(g*16+lm), so a wave's per-ks A-load
// is ONE coalesced 1KB global_load_dwordx4. Also zeroes the 256 B zero-page
// (d_ws re-poisoned before every launch, so rewrite every call).
// ---------------------------------------------------------------------------
__global__ __launch_bounds__(256) void prep_w(const float* __restrict__ w3,
                                              short* __restrict__ Apk,
                                              float* __restrict__ zp) {
    int idx = blockIdx.x * 256 + threadIdx.x;
    if (idx < CC * 320) {
        int co = idx / 320;
        int kk = idx % 320;
        int mh = co >> 5, m = (co >> 4) & 1, lm = co & 15;
        int ks = kk >> 5, g = (kk >> 3) & 3, e = kk & 7;
        int tap = kk >> 6, ci = kk & 63;
        Apk[((((mh * 10 + ks) * 2 + m) * 64) + (g * 16 + lm)) * 8 + e] =
            f2bf(w3[(co * CC + ci) * 5 + tap]);
    }
    if (blockIdx.x == 0 && threadIdx.x < 64) zp[threadIdx.x] = 0.f;
}

// ---------------------------------------------------------------------------
// Kernel 1: fully fused gather + GEMM + combine. One block per (n,h) row;
// 2048 blocks; LDS 19968 B; __launch_bounds__(256,6) (VGPR cap ~85;
// (256,8)'s 64 caused R6's 304 MB scratch spill).
//
// Phase 1 gather: thread owns 4 consecutive channel-pairs (8 channels) at
//   one w-quad -> 8 coalesced float4 loads, pack in-lane, 4x ds_write_b128.
// Phase 2 GEMM: 2x2 wave split, coalesced 1KB Apk A-loads, panel B.
// Phase 3: acc -> t3b bf16 in LDS (aliases dead panel); w7 -> LDS so the
//   combine loop has NO compiler-tracked VMEM loads.
// Phase 4 combine: manual asm prefetch pipeline (RA provably sinks
//   compiler-visible loads: VGPR pinned at 36 in R0/1/9). R10's two
//   ordering holes fixed:
//   (a) explicit s_waitcnt vmcnt(0) AFTER the last __syncthreads -- the
//       barrier does NOT drain untracked asm loads (SIInsertWaitcnts only
//       waits counters it tracked);
//   (b) "memory" clobber on gload4 pins the tracked out-store BELOW the
//       loads, so in-loop vmcnt(1) provably covers all 3 loads (they are
//       older than the store, vmcnt retires in issue order).
//   sched_barrier(0) after every manual waitcnt (rule #18).
//   All shfls UNCONDITIONAL (R7 lesson), selects after.
// ---------------------------------------------------------------------------
__global__ __launch_bounds__(256, 6) void fused(const short* __restrict__ Apk,
                                                const float* __restrict__ x,
                                                const float* __restrict__ w7,
                                                const float* __restrict__ zp,
                                                float* __restrict__ out) {
    __shared__ __align__(16) char smem[19968];
    unsigned*    xsW  = (unsigned*)smem;       // dword view, stride 36
    const short* panel = (const short*)smem;   // phases 1-2 (19008 B)
    short*       t3b  = (short*)smem;          // phase 3-4 (16896 B, aliases)
    float*       wcs  = (float*)(smem + WCS_OFF);  // 3072 B w7 stage

    const int bid = blockIdx.x;
    const int nh  = ((bid & 7) << 8) | (bid >> 3);   // XCD-contiguous h
    const int n   = nh >> 7;
    const int h   = nh & (HH - 1);
    const int tid = threadIdx.x;
    const int lane = tid & 63;
    const int W    = tid >> 6;

    // ---- Phase 1: coalesced gather, in-lane pack, b128 panel writes ----
    {
        const int half = lane >> 5;
        const int wq   = lane & 31;              // w-quad
        const int cp0  = W * 8 + half * 4;       // 4 channel pairs cp0..cp0+3
        const float* b0 = x + ((size_t)(n * CC + 2 * cp0) * HH + h) * WW;
        float4 v[8];
        #pragma unroll
        for (int cc = 0; cc < 8; ++cc)
            v[cc] = *(const float4*)(b0 + (size_t)cc * (HH * WW) + wq * 4);
        #pragma unroll
        for (int k = 0; k < 4; ++k) {
            int wp = wq * 4 + 2 + k;
            uint4 q;
            q.x = pack2bf(v[0][k], v[1][k]);
            q.y = pack2bf(v[2][k], v[3][k]);
            q.z = pack2bf(v[4][k], v[5][k]);
            q.w = pack2bf(v[6][k], v[7][k]);
            *(uint4*)(xsW + wp * 36 + cp0) = q;
        }
        if (tid < 128) {    // zero pad rows wp in {0,1,130,131}
            int wpi = tid >> 5;
            int wpz = (wpi < 2) ? wpi : 128 + wpi;
            xsW[wpz * 36 + (tid & 31)] = 0u;
        }
    }
    __syncthreads();

    // ---- Phase 2: GEMM, MFMA 2x2 wave split ----
    const int lm = lane & 15;
    const int g  = lane >> 4;
    const int mh = W >> 1;           // co half: co-tiles {2mh, 2mh+1}
    const int wh = W & 1;            // w half:  j-tiles wh*4 .. wh*4+3

    floatx4 acc[2][4];
    #pragma unroll
    for (int m = 0; m < 2; ++m)
        #pragma unroll
        for (int j = 0; j < 4; ++j) acc[m][j] = (floatx4){0.f, 0.f, 0.f, 0.f};

    for (int ks = 0; ks < 10; ++ks) {
        const int kbase = ks * 32 + g * 8;
        const int tap   = kbase >> 6;
        const int cib   = kbase & 63;

        const short* ab = Apk + (((mh * 10 + ks) * 2) * 64 + lane) * 8;
        short8 a0 = *(const short8*)ab;                 // m=0, coalesced 1KB
        short8 a1 = *(const short8*)(ab + 64 * 8);      // m=1, coalesced 1KB
        #pragma unroll
        for (int j = 0; j < 4; ++j) {
            int wp = (wh * 4 + j) * 16 + lm + tap;
            short8 b = *(const short8*)&panel[wp * LDS_STRIDE + cib];
            acc[0][j] = __builtin_amdgcn_mfma_f32_16x16x32_bf16(a0, b, acc[0][j], 0, 0, 0);
            acc[1][j] = __builtin_amdgcn_mfma_f32_16x16x32_bf16(a1, b, acc[1][j], 0, 0, 0);
        }
    }
    __syncthreads();   // all waves done READING panel; t3b/wcs may alias it

    // ---- Phase 3a: epilogue: acc -> t3b (bf16) in LDS ----
    #pragma unroll
    for (int m = 0; m < 2; ++m)
        #pragma unroll
        for (int j = 0; j < 4; ++j)
            #pragma unroll
            for (int r = 0; r < 4; ++r) {
                int co = (mh * 2 + m) * 16 + g * 4 + r;
                int w  = (wh * 4 + j) * 16 + lm;
                t3b[co * T3B_STRIDE + w] = f2bf(acc[m][j][r]);
            }

    // ---- Phase 3b: stage w7 -> LDS (stride-12 rows, 16B-aligned) ----
    if (tid < 144) {
        float4 wv = *(const float4*)(w7 + tid * 4);
        #pragma unroll
        for (int e = 0; e < 4; ++e) {
            int idx = tid * 4 + e;
            wcs[(idx / 9) * 12 + (idx % 9)] = wv[e];
        }
    }

    // ---- combine setup ----
    const int w0   = (tid & 31) * 4;
    const int chi  = tid >> 5;            // c = it*8 + chi
    const int lq31 = lane & 31;
    const bool isw = (lq31 == 0);         // w0 == 0
    const bool ise = (lq31 == 31);        // w0 == 124
    const int src31 = lane | 31;          // wrap source (owns cols 124..127)
    const int lsrc  = isw ? lane : lane - 1;
    const int rsrc  = ise ? lane : lane + 1;

    const float* pr[3]; int sr[3];
    const float* xb0 = x + (((size_t)(n * CC + chi)) * HH) * WW;
    #pragma unroll
    for (int r = 0; r < 3; ++r) {
        int hh = h + r - 1;
        bool hok = (unsigned)hh < HH;     // block-uniform per r
        pr[r] = hok ? (xb0 + (size_t)hh * WW + w0) : zp;
        sr[r] = hok ? (8 * HH * WW) : 0;
    }
    int t3o = chi * T3B_STRIDE + w0;
    float* outp = out + ((((size_t)(n * CC + chi)) * HH + h) * WW) + w0;

    // ---- iter-0 prefetch: issue BEFORE the barrier (latency overlaps the
    //      barrier wait), but the barrier does NOT drain untracked loads --
    //      the explicit vmcnt(0) below does.
    float4 curA, curB, curC;
    gload4(curA, pr[0]); pr[0] += sr[0];
    gload4(curB, pr[1]); pr[1] += sr[1];
    gload4(curC, pr[2]); pr[2] += sr[2];

    __syncthreads();   // t3b + wcs written
    asm volatile("s_waitcnt vmcnt(0)" ::: "memory");   // drain iter-0 loads
    __builtin_amdgcn_sched_barrier(0);                 // rule-#18 fence

    // window-row builder: dst[t] = col w0-4+t of the row held in quad c.
    // ALL shfls unconditional (full exec), selects applied afterwards.
    #define BUILD_WIN(dst, c)                                              \
        {                                                                  \
            float l1_ = __shfl((c).y, lsrc);                               \
            float l2_ = __shfl((c).z, lsrc);                               \
            float l3_ = __shfl((c).w, lsrc);                               \
            float r8_ = __shfl((c).x, rsrc);                               \
            float r9_ = __shfl((c).y, rsrc);                               \
            dst[1] = isw ? 0.f : l1_;                                      \
            dst[2] = isw ? 0.f : l2_;                                      \
            dst[3] = isw ? 0.f : l3_;                                      \
            dst[4] = (c).x; dst[5] = (c).y; dst[6] = (c).z; dst[7] = (c).w;\
            dst[8] = ise ? 0.f : r8_;                                      \
            dst[9] = ise ? 0.f : r9_;                                      \
        }

    // ---- Phase 4: combine, manual prefetch pipeline ----
    #pragma unroll
    for (int it = 0; it < 8; ++it) {
        float4 nxtA, nxtB, nxtC;
        if (it < 7) {                      // issue it+1's loads (untracked)
            gload4(nxtA, pr[0]); pr[0] += sr[0];
            gload4(nxtB, pr[1]); pr[1] += sr[1];
            gload4(nxtC, pr[2]); pr[2] += sr[2];
        }

        const float* wrow = wcs + (it * 8 + chi) * 12;   // LDS, broadcast
        float wc[9];
        {
            float4 wv0 = *(const float4*)wrow;
            float4 wv1 = *(const float4*)(wrow + 4);
            wc[0] = wv0.x; wc[1] = wv0.y; wc[2] = wv0.z; wc[3] = wv0.w;
            wc[4] = wv1.x; wc[5] = wv1.y; wc[6] = wv1.z; wc[7] = wv1.w;
            wc[8] = wrow[8];
        }
        ushort4 tv = *(const ushort4*)&t3b[t3o];

        float4 cur[3] = {curA, curB, curC};   // static-indexed aliases

        // roll-wrap values (w==0): cols 125,127 = lane|31's own .y/.w
        float wrap0[3], wrap1[3];
        #pragma unroll
        for (int r = 0; r < 3; ++r) {
            wrap0[r] = __shfl(cur[r].y, src31);
            wrap1[r] = __shfl(cur[r].w, src31);
        }

        // win1 = row h window, cols w0-3..w0+5 (indices 1..9)
        float win1[12];
        BUILD_WIN(win1, cur[1]);

        float t3v[4] = {bf2f(tv.x), bf2f(tv.y), bf2f(tv.z), bf2f(tv.w)};

        float res[4] = {0.f, 0.f, 0.f, 0.f};
        #pragma unroll
        for (int i = 0; i < 3; ++i) {          // i = h-offset row (outer)
            float wini[12];
            if (i == 1) {
                #pragma unroll
                for (int t = 1; t < 10; ++t) wini[t] = win1[t];
            } else {
                BUILD_WIN(wini, cur[i]);
            }
            #pragma unroll
            for (int j = 0; j < 3; ++j) {
                #pragma unroll
                for (int e = 0; e < 4; ++e) {
                    float lhs = win1[e + 2 * i + 2];      // col w+2(i-1), row h
                    float rhs = wini[e + 2 * j + 1];      // col w+2j-3, row h+i-1
                    if (e == 0)
                        rhs = isw ? ((j == 0) ? wrap0[i]
                                   : (j == 1) ? wrap1[i] : 0.f)
                                  : rhs;
                    res[e] = fmaf(wc[j * 3 + i], fmaxf(lhs, rhs), res[e]);
                }
            }
        }
        float4 o;
        o.x = res[0] * t3v[0]; o.y = res[1] * t3v[1];
        o.z = res[2] * t3v[2]; o.w = res[3] * t3v[3];
        *(float4*)outp = o;

        t3o  += 8 * T3B_STRIDE;
        outp += (size_t)8 * HH * WW;

        if (it < 7) {
            // Loads are pinned OLDER than this iter's store ("memory"
            // clobber on gload4): vmcnt(1) => at most the store remains
            // outstanding, all 3 loads complete.
            asm volatile("s_waitcnt vmcnt(1)" ::: "memory");
            __builtin_amdgcn_sched_barrier(0);   // rule-#18 fence
            curA = nxtA; curB = nxtB; curC = nxtC;
        }
    }
    #undef BUILD_WIN
}

extern "C" void kernel_launch(void* const* d_in, const int* in_sizes, int n_in,
                              void* d_out, int out_size, void* d_ws, size_t ws_size,
                              hipStream_t stream) {
    const float* x  = (const float*)d_in[0];
    const float* w3 = (const float*)d_in[1];
    const float* w7 = (const float*)d_in[2];
    float* out = (float*)d_out;

    short* Apk = (short*)d_ws;                       // 40960 B packed A
    float* zp  = (float*)((char*)d_ws + 40960);      // 256 B zero page

    prep_w<<<(CC * 320 + 255) / 256, 256, 0, stream>>>(w3, Apk, zp);
    fused<<<NN * HH, 256, 0, stream>>>(Apk, x, w7, zp, out);
}